// Round 1
// baseline (3912.930 us; speedup 1.0000x reference)
//
#include <hip/hip_runtime.h>

#define TPB 256

// ---------------- index dtype detection + normalization ----------------
// If edge_index arrived as int64 (little-endian, values < 2^31), every odd
// 32-bit word is zero. If int32, odd words are random node indices.
__global__ void detect_kernel(const unsigned int* __restrict__ w, int* __restrict__ flag) {
    __shared__ int any;
    if (threadIdx.x == 0) any = 0;
    __syncthreads();
    int nz = 0;
    for (int k = threadIdx.x; k < 1024; k += blockDim.x)
        if (w[2 * k + 1] != 0u) nz = 1;
    if (nz) atomicOr(&any, 1);
    __syncthreads();
    if (threadIdx.x == 0) *flag = (any == 0) ? 1 : 0;  // 1 => int64
}

__global__ void convert_kernel(const void* __restrict__ ei, const int* __restrict__ flag,
                               int* __restrict__ out, long long n) {
    long long i = blockIdx.x * (long long)blockDim.x + threadIdx.x;
    if (i >= n) return;
    if (*flag) out[i] = (int)((const long long*)ei)[i];
    else       out[i] = ((const int*)ei)[i];
}

// ---------------- degree / norm ----------------
__global__ void init_deg_kernel(float* __restrict__ deg, int N) {
    int n = blockIdx.x * blockDim.x + threadIdx.x;
    if (n < N) deg[n] = 1.0f;  // self-loop
}

__global__ void count_deg_kernel(const int* __restrict__ dstv, float* __restrict__ deg, int E) {
    int e = blockIdx.x * blockDim.x + threadIdx.x;
    if (e < E) atomicAdd(&deg[dstv[e]], 1.0f);
}

__global__ void dinv_kernel(float* __restrict__ deg, int N) {
    int n = blockIdx.x * blockDim.x + threadIdx.x;
    if (n < N) deg[n] = rsqrtf(deg[n]);
}

// ---------------- layer 1: hs1 = dinv * (x @ W1); acc1 = hs1 (self-loop) ----------------
__global__ __launch_bounds__(TPB) void gemm1_kernel(
    const float* __restrict__ x, const float* __restrict__ W,
    const float* __restrict__ dinv, float* __restrict__ hs,
    float* __restrict__ acc, int N) {
    __shared__ float Ws[128 * 16];
    for (int i = threadIdx.x; i < 128 * 16; i += blockDim.x) Ws[i] = W[i];
    __syncthreads();
    int n = blockIdx.x * blockDim.x + threadIdx.x;
    if (n >= N) return;
    const float4* xp = (const float4*)(x + (size_t)n * 128);
    float a[16];
#pragma unroll
    for (int j = 0; j < 16; ++j) a[j] = 0.f;
#pragma unroll 4
    for (int k4 = 0; k4 < 32; ++k4) {
        float4 xv = xp[k4];
        const float* wr = &Ws[k4 * 64];
#pragma unroll
        for (int j = 0; j < 16; ++j) a[j] += xv.x * wr[j];
#pragma unroll
        for (int j = 0; j < 16; ++j) a[j] += xv.y * wr[16 + j];
#pragma unroll
        for (int j = 0; j < 16; ++j) a[j] += xv.z * wr[32 + j];
#pragma unroll
        for (int j = 0; j < 16; ++j) a[j] += xv.w * wr[48 + j];
    }
    float sc = dinv[n];
    float4* hp = (float4*)(hs + (size_t)n * 16);
    float4* ap = (float4*)(acc + (size_t)n * 16);
#pragma unroll
    for (int j4 = 0; j4 < 4; ++j4) {
        float4 v;
        v.x = a[j4 * 4 + 0] * sc; v.y = a[j4 * 4 + 1] * sc;
        v.z = a[j4 * 4 + 2] * sc; v.w = a[j4 * 4 + 3] * sc;
        hp[j4] = v; ap[j4] = v;
    }
}

// ---------------- edge scatter, 16 features ----------------
__global__ __launch_bounds__(TPB) void scatter1_kernel(
    const int* __restrict__ idx, const float* __restrict__ hs,
    float* __restrict__ acc, int E) {
    int e = blockIdx.x * blockDim.x + threadIdx.x;
    if (e >= E) return;
    int s = idx[e];
    int d = idx[E + e];
    const float4* hp = (const float4*)(hs + (size_t)s * 16);
    float4 v0 = hp[0], v1 = hp[1], v2 = hp[2], v3 = hp[3];
    float* ap = acc + (size_t)d * 16;
    atomicAdd(ap + 0,  v0.x); atomicAdd(ap + 1,  v0.y);
    atomicAdd(ap + 2,  v0.z); atomicAdd(ap + 3,  v0.w);
    atomicAdd(ap + 4,  v1.x); atomicAdd(ap + 5,  v1.y);
    atomicAdd(ap + 6,  v1.z); atomicAdd(ap + 7,  v1.w);
    atomicAdd(ap + 8,  v2.x); atomicAdd(ap + 9,  v2.y);
    atomicAdd(ap + 10, v2.z); atomicAdd(ap + 11, v2.w);
    atomicAdd(ap + 12, v3.x); atomicAdd(ap + 13, v3.y);
    atomicAdd(ap + 14, v3.z); atomicAdd(ap + 15, v3.w);
}

// ---------------- layer 2: relu(dinv*acc1 + b1) @ W2, pre-scale by dinv ----------------
__global__ __launch_bounds__(TPB) void layer2_kernel(
    const float* __restrict__ acc1, const float* __restrict__ dinv,
    const float* __restrict__ W2, const float* __restrict__ b1,
    float* __restrict__ hs2, float* __restrict__ acc2, int N) {
    __shared__ float Ws[16 * 7];
    __shared__ float bs[16];
    for (int i = threadIdx.x; i < 16 * 7; i += blockDim.x) Ws[i] = W2[i];
    if (threadIdx.x < 16) bs[threadIdx.x] = b1[threadIdx.x];
    __syncthreads();
    int n = blockIdx.x * blockDim.x + threadIdx.x;
    if (n >= N) return;
    float sc = dinv[n];
    const float4* ap = (const float4*)(acc1 + (size_t)n * 16);
    float v[16];
#pragma unroll
    for (int j4 = 0; j4 < 4; ++j4) {
        float4 t = ap[j4];
        v[j4 * 4 + 0] = fmaxf(0.f, sc * t.x + bs[j4 * 4 + 0]);
        v[j4 * 4 + 1] = fmaxf(0.f, sc * t.y + bs[j4 * 4 + 1]);
        v[j4 * 4 + 2] = fmaxf(0.f, sc * t.z + bs[j4 * 4 + 2]);
        v[j4 * 4 + 3] = fmaxf(0.f, sc * t.w + bs[j4 * 4 + 3]);
    }
    float h[7];
#pragma unroll
    for (int j = 0; j < 7; ++j) h[j] = 0.f;
#pragma unroll
    for (int i = 0; i < 16; ++i)
#pragma unroll
        for (int j = 0; j < 7; ++j) h[j] += v[i] * Ws[i * 7 + j];
    float4 o0, o1;
    o0.x = h[0] * sc; o0.y = h[1] * sc; o0.z = h[2] * sc; o0.w = h[3] * sc;
    o1.x = h[4] * sc; o1.y = h[5] * sc; o1.z = h[6] * sc; o1.w = 0.f;
    float4* hp = (float4*)(hs2 + (size_t)n * 8);
    float4* cp = (float4*)(acc2 + (size_t)n * 8);
    hp[0] = o0; hp[1] = o1; cp[0] = o0; cp[1] = o1;
}

// ---------------- edge scatter, 7 features ----------------
__global__ __launch_bounds__(TPB) void scatter2_kernel(
    const int* __restrict__ idx, const float* __restrict__ hs,
    float* __restrict__ acc, int E) {
    int e = blockIdx.x * blockDim.x + threadIdx.x;
    if (e >= E) return;
    int s = idx[e];
    int d = idx[E + e];
    const float4* hp = (const float4*)(hs + (size_t)s * 8);
    float4 v0 = hp[0], v1 = hp[1];
    float* ap = acc + (size_t)d * 8;
    atomicAdd(ap + 0, v0.x); atomicAdd(ap + 1, v0.y);
    atomicAdd(ap + 2, v0.z); atomicAdd(ap + 3, v0.w);
    atomicAdd(ap + 4, v1.x); atomicAdd(ap + 5, v1.y);
    atomicAdd(ap + 6, v1.z);
}

// ---------------- final: bias + log_softmax ----------------
__global__ __launch_bounds__(TPB) void final_kernel(
    const float* __restrict__ acc2, const float* __restrict__ dinv,
    const float* __restrict__ b2, float* __restrict__ out, int N) {
    int n = blockIdx.x * blockDim.x + threadIdx.x;
    if (n >= N) return;
    float sc = dinv[n];
    const float4* ap = (const float4*)(acc2 + (size_t)n * 8);
    float4 t0 = ap[0], t1 = ap[1];
    float v[7];
    v[0] = sc * t0.x + b2[0]; v[1] = sc * t0.y + b2[1];
    v[2] = sc * t0.z + b2[2]; v[3] = sc * t0.w + b2[3];
    v[4] = sc * t1.x + b2[4]; v[5] = sc * t1.y + b2[5];
    v[6] = sc * t1.z + b2[6];
    float m = v[0];
#pragma unroll
    for (int j = 1; j < 7; ++j) m = fmaxf(m, v[j]);
    float ssum = 0.f;
#pragma unroll
    for (int j = 0; j < 7; ++j) ssum += __expf(v[j] - m);
    float l = m + __logf(ssum);
    float* op = out + (size_t)n * 7;
#pragma unroll
    for (int j = 0; j < 7; ++j) op[j] = v[j] - l;
}

extern "C" void kernel_launch(void* const* d_in, const int* in_sizes, int n_in,
                              void* d_out, int out_size, void* d_ws, size_t ws_size,
                              hipStream_t stream) {
    const float* x  = (const float*)d_in[0];
    const void*  ei = d_in[1];
    const float* W1 = (const float*)d_in[2];
    const float* b1 = (const float*)d_in[3];
    const float* W2 = (const float*)d_in[4];
    const float* b2 = (const float*)d_in[5];
    float* out = (float*)d_out;

    const int Hh  = in_sizes[3];            // 16
    const int Fin = in_sizes[2] / Hh;       // 128
    const int N   = in_sizes[0] / Fin;      // 100000
    const long long twoE = in_sizes[1];
    const int E = (int)(twoE / 2);          // 3200000
    (void)n_in; (void)out_size; (void)ws_size;

    char* p = (char*)d_ws;
    auto alloc = [&](size_t bytes) {
        char* r = p;
        p += (bytes + 63) & ~(size_t)63;
        return r;
    };
    int*   flag = (int*)  alloc(sizeof(int));
    int*   idx  = (int*)  alloc(sizeof(int) * (size_t)twoE);
    float* deg  = (float*)alloc(sizeof(float) * (size_t)N);
    float* hs1  = (float*)alloc(sizeof(float) * (size_t)N * 16);
    float* acc1 = (float*)alloc(sizeof(float) * (size_t)N * 16);
    float* hs2  = (float*)alloc(sizeof(float) * (size_t)N * 8);
    float* acc2 = (float*)alloc(sizeof(float) * (size_t)N * 8);

    detect_kernel<<<1, 256, 0, stream>>>((const unsigned int*)ei, flag);
    int cb = (int)((twoE + TPB - 1) / TPB);
    convert_kernel<<<cb, TPB, 0, stream>>>(ei, flag, idx, twoE);

    init_deg_kernel<<<(N + TPB - 1) / TPB, TPB, 0, stream>>>(deg, N);
    count_deg_kernel<<<(E + TPB - 1) / TPB, TPB, 0, stream>>>(idx + E, deg, E);
    dinv_kernel<<<(N + TPB - 1) / TPB, TPB, 0, stream>>>(deg, N);

    gemm1_kernel<<<(N + TPB - 1) / TPB, TPB, 0, stream>>>(x, W1, deg, hs1, acc1, N);
    scatter1_kernel<<<(E + TPB - 1) / TPB, TPB, 0, stream>>>(idx, hs1, acc1, E);
    layer2_kernel<<<(N + TPB - 1) / TPB, TPB, 0, stream>>>(acc1, deg, W2, b1, hs2, acc2, N);
    scatter2_kernel<<<(E + TPB - 1) / TPB, TPB, 0, stream>>>(idx, hs2, acc2, E);
    final_kernel<<<(N + TPB - 1) / TPB, TPB, 0, stream>>>(acc2, deg, b2, out, N);
}

// Round 2
// 564.755 us; speedup vs baseline: 6.9285x; 6.9285x over previous
//
#include <hip/hip_runtime.h>

#define TPB 256
#define SCAN_BLK 256
#define SCAN_IPT 4
#define SCAN_TILE (SCAN_BLK * SCAN_IPT)

// ---------------- index dtype detection + normalization ----------------
__global__ void detect_kernel(const unsigned int* __restrict__ w, int* __restrict__ flag) {
    __shared__ int any;
    if (threadIdx.x == 0) any = 0;
    __syncthreads();
    int nz = 0;
    for (int k = threadIdx.x; k < 1024; k += blockDim.x)
        if (w[2 * k + 1] != 0u) nz = 1;
    if (nz) atomicOr(&any, 1);
    __syncthreads();
    if (threadIdx.x == 0) *flag = (any == 0) ? 1 : 0;  // 1 => int64
}

__global__ void convert_kernel(const void* __restrict__ ei, const int* __restrict__ flag,
                               int* __restrict__ out, long long n) {
    long long i = blockIdx.x * (long long)blockDim.x + threadIdx.x;
    if (i >= n) return;
    if (*flag) out[i] = (int)((const long long*)ei)[i];
    else       out[i] = ((const int*)ei)[i];
}

// ---------------- CSR build ----------------
__global__ void zero_kernel(int* __restrict__ p, int n) {
    int i = blockIdx.x * blockDim.x + threadIdx.x;
    if (i < n) p[i] = 0;
}

__global__ void count_deg_kernel(const int* __restrict__ dstv, int* __restrict__ deg, int E) {
    int e = blockIdx.x * blockDim.x + threadIdx.x;
    if (e < E) atomicAdd(&deg[dstv[e]], 1);
}

// block-level scan: write per-item local-exclusive prefix + block totals; also dinv
__global__ __launch_bounds__(SCAN_BLK) void scan1_kernel(
    const int* __restrict__ deg, int* __restrict__ row, float* __restrict__ dinv,
    int* __restrict__ blockSums, int N) {
    __shared__ int sh[SCAN_BLK];
    int base = blockIdx.x * SCAN_TILE + threadIdx.x * SCAN_IPT;
    int d[SCAN_IPT];
    int t = 0;
#pragma unroll
    for (int i = 0; i < SCAN_IPT; ++i) {
        int n = base + i;
        int v = (n < N) ? deg[n] : 0;
        d[i] = v; t += v;
        if (n < N) dinv[n] = rsqrtf((float)(v + 1));  // +1 self-loop
    }
    sh[threadIdx.x] = t;
    __syncthreads();
    for (int off = 1; off < SCAN_BLK; off <<= 1) {
        int v = (threadIdx.x >= off) ? sh[threadIdx.x - off] : 0;
        __syncthreads();
        sh[threadIdx.x] += v;
        __syncthreads();
    }
    int excl = sh[threadIdx.x] - t;
    if (threadIdx.x == SCAN_BLK - 1) blockSums[blockIdx.x] = sh[SCAN_BLK - 1];
    int run = excl;
#pragma unroll
    for (int i = 0; i < SCAN_IPT; ++i) {
        int n = base + i;
        if (n < N) row[n] = run;
        run += d[i];
    }
}

__global__ __launch_bounds__(1024) void scan2_kernel(int* __restrict__ blockSums, int nb) {
    __shared__ int sh[1024];
    int t = threadIdx.x;
    int v = (t < nb) ? blockSums[t] : 0;
    sh[t] = v;
    __syncthreads();
    for (int off = 1; off < 1024; off <<= 1) {
        int u = (t >= off) ? sh[t - off] : 0;
        __syncthreads();
        sh[t] += u;
        __syncthreads();
    }
    if (t < nb) blockSums[t] = sh[t] - v;  // exclusive
}

__global__ void scan3_kernel(int* __restrict__ row, int* __restrict__ cursor,
                             const int* __restrict__ blockSums, int N) {
    int n = blockIdx.x * blockDim.x + threadIdx.x;
    if (n >= N) return;
    int r = row[n] + blockSums[n / SCAN_TILE];
    row[n] = r;
    cursor[n] = r;
}

__global__ void place_kernel(const int* __restrict__ idx, int* __restrict__ cursor,
                             int* __restrict__ csr_src, int E) {
    int e = blockIdx.x * blockDim.x + threadIdx.x;
    if (e >= E) return;
    int s = idx[e];
    int d = idx[E + e];
    int pos = atomicAdd(&cursor[d], 1);
    csr_src[pos] = s;
}

// ---------------- layer 1 GEMM: hs1 = dinv * (x @ W1) ----------------
__global__ __launch_bounds__(TPB) void gemm1_kernel(
    const float* __restrict__ x, const float* __restrict__ W,
    const float* __restrict__ dinv, float* __restrict__ hs, int N) {
    __shared__ float Ws[128 * 16];
    for (int i = threadIdx.x; i < 128 * 16; i += blockDim.x) Ws[i] = W[i];
    __syncthreads();
    int n = blockIdx.x * blockDim.x + threadIdx.x;
    if (n >= N) return;
    const float4* xp = (const float4*)(x + (size_t)n * 128);
    float a[16];
#pragma unroll
    for (int j = 0; j < 16; ++j) a[j] = 0.f;
#pragma unroll 4
    for (int k4 = 0; k4 < 32; ++k4) {
        float4 xv = xp[k4];
        const float* wr = &Ws[k4 * 64];
#pragma unroll
        for (int j = 0; j < 16; ++j) a[j] += xv.x * wr[j];
#pragma unroll
        for (int j = 0; j < 16; ++j) a[j] += xv.y * wr[16 + j];
#pragma unroll
        for (int j = 0; j < 16; ++j) a[j] += xv.z * wr[32 + j];
#pragma unroll
        for (int j = 0; j < 16; ++j) a[j] += xv.w * wr[48 + j];
    }
    float sc = dinv[n];
    float4* hp = (float4*)(hs + (size_t)n * 16);
#pragma unroll
    for (int j4 = 0; j4 < 4; ++j4) {
        float4 v;
        v.x = a[j4 * 4 + 0] * sc; v.y = a[j4 * 4 + 1] * sc;
        v.z = a[j4 * 4 + 2] * sc; v.w = a[j4 * 4 + 3] * sc;
        hp[j4] = v;
    }
}

// ---------------- fused aggregate-1 + layer2 ----------------
__global__ __launch_bounds__(TPB) void agg1_kernel(
    const float* __restrict__ hs1, const int* __restrict__ csr_src,
    const int* __restrict__ row, const int* __restrict__ degi,
    const float* __restrict__ dinv, const float* __restrict__ W2,
    const float* __restrict__ b1, float* __restrict__ hs2, int N) {
    __shared__ float Ws[16 * 7];
    __shared__ float bs[16];
    for (int i = threadIdx.x; i < 16 * 7; i += blockDim.x) Ws[i] = W2[i];
    if (threadIdx.x < 16) bs[threadIdx.x] = b1[threadIdx.x];
    __syncthreads();
    int n = blockIdx.x * blockDim.x + threadIdx.x;
    if (n >= N) return;
    const float4* sp = (const float4*)(hs1 + (size_t)n * 16);
    float4 a0 = sp[0], a1 = sp[1], a2 = sp[2], a3 = sp[3];  // self-loop
    int st = row[n], cnt = degi[n];
    for (int i = 0; i < cnt; ++i) {
        int s = csr_src[st + i];
        const float4* p = (const float4*)(hs1 + (size_t)s * 16);
        float4 q0 = p[0], q1 = p[1], q2 = p[2], q3 = p[3];
        a0.x += q0.x; a0.y += q0.y; a0.z += q0.z; a0.w += q0.w;
        a1.x += q1.x; a1.y += q1.y; a1.z += q1.z; a1.w += q1.w;
        a2.x += q2.x; a2.y += q2.y; a2.z += q2.z; a2.w += q2.w;
        a3.x += q3.x; a3.y += q3.y; a3.z += q3.z; a3.w += q3.w;
    }
    float sc = dinv[n];
    float v[16];
    v[0]  = fmaxf(0.f, sc * a0.x + bs[0]);  v[1]  = fmaxf(0.f, sc * a0.y + bs[1]);
    v[2]  = fmaxf(0.f, sc * a0.z + bs[2]);  v[3]  = fmaxf(0.f, sc * a0.w + bs[3]);
    v[4]  = fmaxf(0.f, sc * a1.x + bs[4]);  v[5]  = fmaxf(0.f, sc * a1.y + bs[5]);
    v[6]  = fmaxf(0.f, sc * a1.z + bs[6]);  v[7]  = fmaxf(0.f, sc * a1.w + bs[7]);
    v[8]  = fmaxf(0.f, sc * a2.x + bs[8]);  v[9]  = fmaxf(0.f, sc * a2.y + bs[9]);
    v[10] = fmaxf(0.f, sc * a2.z + bs[10]); v[11] = fmaxf(0.f, sc * a2.w + bs[11]);
    v[12] = fmaxf(0.f, sc * a3.x + bs[12]); v[13] = fmaxf(0.f, sc * a3.y + bs[13]);
    v[14] = fmaxf(0.f, sc * a3.z + bs[14]); v[15] = fmaxf(0.f, sc * a3.w + bs[15]);
    float h[7];
#pragma unroll
    for (int j = 0; j < 7; ++j) h[j] = 0.f;
#pragma unroll
    for (int i = 0; i < 16; ++i)
#pragma unroll
        for (int j = 0; j < 7; ++j) h[j] += v[i] * Ws[i * 7 + j];
    float4 o0, o1;
    o0.x = h[0] * sc; o0.y = h[1] * sc; o0.z = h[2] * sc; o0.w = h[3] * sc;
    o1.x = h[4] * sc; o1.y = h[5] * sc; o1.z = h[6] * sc; o1.w = 0.f;
    float4* hp = (float4*)(hs2 + (size_t)n * 8);
    hp[0] = o0; hp[1] = o1;
}

// ---------------- fused aggregate-2 + bias + log_softmax ----------------
__global__ __launch_bounds__(TPB) void agg2_kernel(
    const float* __restrict__ hs2, const int* __restrict__ csr_src,
    const int* __restrict__ row, const int* __restrict__ degi,
    const float* __restrict__ dinv, const float* __restrict__ b2,
    float* __restrict__ out, int N) {
    __shared__ float bs[8];
    if (threadIdx.x < 7) bs[threadIdx.x] = b2[threadIdx.x];
    __syncthreads();
    int n = blockIdx.x * blockDim.x + threadIdx.x;
    if (n >= N) return;
    const float4* sp = (const float4*)(hs2 + (size_t)n * 8);
    float4 a0 = sp[0], a1 = sp[1];  // self-loop
    int st = row[n], cnt = degi[n];
    for (int i = 0; i < cnt; ++i) {
        int s = csr_src[st + i];
        const float4* p = (const float4*)(hs2 + (size_t)s * 8);
        float4 q0 = p[0], q1 = p[1];
        a0.x += q0.x; a0.y += q0.y; a0.z += q0.z; a0.w += q0.w;
        a1.x += q1.x; a1.y += q1.y; a1.z += q1.z;
    }
    float sc = dinv[n];
    float v[7];
    v[0] = sc * a0.x + bs[0]; v[1] = sc * a0.y + bs[1];
    v[2] = sc * a0.z + bs[2]; v[3] = sc * a0.w + bs[3];
    v[4] = sc * a1.x + bs[4]; v[5] = sc * a1.y + bs[5];
    v[6] = sc * a1.z + bs[6];
    float m = v[0];
#pragma unroll
    for (int j = 1; j < 7; ++j) m = fmaxf(m, v[j]);
    float ssum = 0.f;
#pragma unroll
    for (int j = 0; j < 7; ++j) ssum += __expf(v[j] - m);
    float l = m + __logf(ssum);
    float* op = out + (size_t)n * 7;
#pragma unroll
    for (int j = 0; j < 7; ++j) op[j] = v[j] - l;
}

extern "C" void kernel_launch(void* const* d_in, const int* in_sizes, int n_in,
                              void* d_out, int out_size, void* d_ws, size_t ws_size,
                              hipStream_t stream) {
    const float* x  = (const float*)d_in[0];
    const void*  ei = d_in[1];
    const float* W1 = (const float*)d_in[2];
    const float* b1 = (const float*)d_in[3];
    const float* W2 = (const float*)d_in[4];
    const float* b2 = (const float*)d_in[5];
    float* out = (float*)d_out;

    const int Hh  = in_sizes[3];            // 16
    const int Fin = in_sizes[2] / Hh;       // 128
    const int N   = in_sizes[0] / Fin;      // 100000
    const long long twoE = in_sizes[1];
    const int E = (int)(twoE / 2);          // 3200000
    (void)n_in; (void)out_size; (void)ws_size;

    char* p = (char*)d_ws;
    auto alloc = [&](size_t bytes) {
        char* r = p;
        p += (bytes + 63) & ~(size_t)63;
        return r;
    };
    int*   flag    = (int*)alloc(sizeof(int));
    int*   idx     = (int*)alloc(sizeof(int) * (size_t)twoE);   // dead after place
    int*   degi    = (int*)alloc(sizeof(int) * (size_t)N);
    int*   row     = (int*)alloc(sizeof(int) * (size_t)N);
    int*   cursor  = (int*)alloc(sizeof(int) * (size_t)N);
    float* dinv    = (float*)alloc(sizeof(float) * (size_t)N);
    int*   bsums   = (int*)alloc(sizeof(int) * 1024);
    int*   csr_src = (int*)alloc(sizeof(int) * (size_t)E);
    // alias hs1/hs2 into the dead idx region (gemm1 runs after place_kernel)
    float* hs1 = (float*)idx;                      // N*16 floats = 6.4 MB
    float* hs2 = (float*)(idx + (size_t)N * 16);   // N*8  floats = 3.2 MB

    detect_kernel<<<1, 256, 0, stream>>>((const unsigned int*)ei, flag);
    int cb = (int)((twoE + TPB - 1) / TPB);
    convert_kernel<<<cb, TPB, 0, stream>>>(ei, flag, idx, twoE);

    int nBlkN = (N + TPB - 1) / TPB;
    int nBlkE = (E + TPB - 1) / TPB;
    int nb = (N + SCAN_TILE - 1) / SCAN_TILE;

    zero_kernel<<<nBlkN, TPB, 0, stream>>>(degi, N);
    count_deg_kernel<<<nBlkE, TPB, 0, stream>>>(idx + E, degi, E);
    scan1_kernel<<<nb, SCAN_BLK, 0, stream>>>(degi, row, dinv, bsums, N);
    scan2_kernel<<<1, 1024, 0, stream>>>(bsums, nb);
    scan3_kernel<<<nBlkN, TPB, 0, stream>>>(row, cursor, bsums, N);
    place_kernel<<<nBlkE, TPB, 0, stream>>>(idx, cursor, csr_src, E);

    gemm1_kernel<<<nBlkN, TPB, 0, stream>>>(x, W1, dinv, hs1, N);
    agg1_kernel<<<nBlkN, TPB, 0, stream>>>(hs1, csr_src, row, degi, dinv, W2, b1, hs2, N);
    agg2_kernel<<<nBlkN, TPB, 0, stream>>>(hs2, csr_src, row, degi, dinv, b2, out, N);
}